// Round 15
// baseline (152.693 us; speedup 1.0000x reference)
//
#include <hip/hip_runtime.h>
#include <stdint.h>

#define KD 4096
#define ND 4096
#define BK 64
#define NT 64            // K-tiles == HQQ groups along K (GROUP_SIZE == BK)

typedef __bf16 bf16x8 __attribute__((ext_vector_type(8)));
typedef float f32x4 __attribute__((ext_vector_type(4)));
typedef int   i32x4 __attribute__((ext_vector_type(4)));

__device__ __forceinline__ uint32_t f32_to_bf16(float f) {
    union { float f; uint32_t u; } v; v.f = f;
    return (v.u + 0x7FFFu + ((v.u >> 16) & 1u)) >> 16;
}

#define GLDS16(gp, lp) \
    __builtin_amdgcn_global_load_lds((const __attribute__((address_space(1))) void*)(gp), \
                                     (__attribute__((address_space(3))) void*)(lp), 16, 0, 0)

// ---------------------------------------------------------------------------
// xq: per-row quantize x (fp32) -> i8 (sx = rowabsmax/127), plus per-group
// sums xs[r][g] = sum_{k in g} xi, stored as EXACT bf16 split hi/lo
// (hi = multiple of 32, |hi/32| <= 254 -> bf16-exact; lo in [0,32) exact).
// ---------------------------------------------------------------------------
__global__ void xq_kernel(const float* __restrict__ x,
                          int8_t* __restrict__ xi,
                          float* __restrict__ sx,
                          uint16_t* __restrict__ xsh,
                          uint16_t* __restrict__ xsl) {
    const int r = blockIdx.x;
    const int t = threadIdx.x;           // 256 threads, 16 elems each
    const float4* xp = (const float4*)(x + (size_t)r * KD) + t * 4;
    float4 v0 = xp[0], v1 = xp[1], v2 = xp[2], v3 = xp[3];
    float vv[16] = {v0.x, v0.y, v0.z, v0.w, v1.x, v1.y, v1.z, v1.w,
                    v2.x, v2.y, v2.z, v2.w, v3.x, v3.y, v3.z, v3.w};
    float am = 0.f;
#pragma unroll
    for (int j = 0; j < 16; ++j) am = fmaxf(am, fabsf(vv[j]));
#pragma unroll
    for (int off = 32; off; off >>= 1) am = fmaxf(am, __shfl_xor(am, off));
    __shared__ float red[4];
    __shared__ int gsum[256];
    if ((t & 63) == 0) red[t >> 6] = am;
    __syncthreads();
    am = fmaxf(fmaxf(red[0], red[1]), fmaxf(red[2], red[3]));
    am = fmaxf(am, 1e-20f);
    const float inv = 127.f / am;
    int q[16]; int ssum = 0;
#pragma unroll
    for (int j = 0; j < 16; ++j) {
        int qi = __float2int_rn(vv[j] * inv);
        q[j] = qi; ssum += qi;
    }
    uint32_t w[4];
#pragma unroll
    for (int p = 0; p < 4; ++p)
        w[p] = (q[4*p] & 255) | ((q[4*p+1] & 255) << 8) |
               ((q[4*p+2] & 255) << 16) | ((uint32_t)(q[4*p+3] & 255) << 24);
    uint4 pk = {w[0], w[1], w[2], w[3]};
    *(uint4*)(xi + (size_t)r * KD + t * 16) = pk;
    gsum[t] = ssum;
    __syncthreads();
    if (t < 64) {
        int xs = gsum[t*4] + gsum[t*4+1] + gsum[t*4+2] + gsum[t*4+3];
        int hi = (xs >> 5) << 5;
        int lo = xs - hi;
        xsh[(size_t)r * 64 + t] = (uint16_t)f32_to_bf16((float)hi);
        xsl[(size_t)r * 64 + t] = (uint16_t)f32_to_bf16((float)lo);
    }
    if (t == 0) sx[r] = am / 127.f;
}

// ---------------------------------------------------------------------------
// wq: unpack int32-widened packed bytes -> i8 nibbles Wi[o][k] (rows <2048 =
// high nibble, >=2048 = low). Weights EXACT in i8.
// ---------------------------------------------------------------------------
__global__ void wq_kernel(const int* __restrict__ Wq, int8_t* __restrict__ Wi) {
    int t = blockIdx.x * 256 + threadIdx.x;   // 1048576 threads x 8 ints
    int o  = t >> 9;
    int i0 = (t & 511) << 3;
    const uint4* wp = (const uint4*)Wq;
    uint4 pa = wp[t * 2], pb = wp[t * 2 + 1];
    uint32_t v[8] = {pa.x, pa.y, pa.z, pa.w, pb.x, pb.y, pb.z, pb.w};
    uint32_t hi0 = 0, hi1 = 0, lo0 = 0, lo1 = 0;
#pragma unroll
    for (int j = 0; j < 4; ++j) {
        hi0 |= ((v[j] >> 4) & 15u) << (8 * j);
        lo0 |= (v[j] & 15u) << (8 * j);
        hi1 |= ((v[4 + j] >> 4) & 15u) << (8 * j);
        lo1 |= (v[4 + j] & 15u) << (8 * j);
    }
    uint2 h = {hi0, hi1}, l = {lo0, lo1};
    *(uint2*)(Wi + (size_t)o * KD + i0)          = h;
    *(uint2*)(Wi + (size_t)(o + 2048) * KD + i0) = l;
}

// ---------------------------------------------------------------------------
// sz: sT[kt][o] = scale[o*64+kt] (transposed, so GEMM reads are contiguous);
// zsneg[o][g] = bf16(-scale*zero).
// ---------------------------------------------------------------------------
__global__ void sz_kernel(const float* __restrict__ scale,
                          const float* __restrict__ zero,
                          float* __restrict__ sT,
                          uint16_t* __restrict__ zsneg) {
    __shared__ float tile[64][65];
    const int o0 = blockIdx.x * 64;
    const int t = threadIdx.x;            // 256
#pragma unroll
    for (int j = 0; j < 16; ++j) {
        int idx = t * 16 + j;
        int oi = idx >> 6, g = idx & 63;
        float s = scale[(size_t)(o0 + oi) * 64 + g];
        float z = zero[(size_t)(o0 + oi) * 64 + g];
        tile[g][oi] = s;
        zsneg[(size_t)(o0 + oi) * 64 + g] = (uint16_t)f32_to_bf16(-s * z);
    }
    __syncthreads();
#pragma unroll
    for (int j = 0; j < 16; ++j) {
        int idx = t * 16 + j;
        int g = idx >> 6, oi = idx & 63;
        sT[(size_t)g * 4096 + o0 + oi] = tile[g][oi];
    }
}

// ---------------------------------------------------------------------------
// i8 GEMM: 256x256 tile, BK=64, 16 waves (4Mx4N of 64x64) @ 1024 thr.
// Per tile = one HQQ group: 16x mfma_i32_16x16x64_i8 (C=0) + per-frag
// epilogue acc[m][n] += s[col]*(float)iacc  (s from sT, per-column scalar).
// LDS [2buf][2mat][256][64] i8 = 64 KiB (rows 64 B: frag reads hit 8
// lanes/bank-group = minimum aliasing, no swizzle needed). R9-proven fences:
// one VM(0)+BAR per tile, stages target opposite buffer.
// Zero-point correction appended as 2 bf16 K=64 tiles: acc += xs_hi/lo x
// (-s*z); then final y = sx[row]*acc.
// ---------------------------------------------------------------------------
#define BAR()  asm volatile("s_barrier" ::: "memory")
#define LGKM0() do { asm volatile("s_waitcnt lgkmcnt(0)" ::: "memory"); \
                     __builtin_amdgcn_sched_barrier(0); } while (0)
#define VM(N)  asm volatile("s_waitcnt vmcnt(" #N ")" ::: "memory")

#define STI(GP, BUF, MAT, KB) \
    GLDS16((GP) + (size_t)grow * KD + (KB) + slot16 * 16, \
           ldsb + ((BUF) * 2 + (MAT)) * 16384 + tid * 16)

#define ST_CORR(GSRC, LOFF) do {                                                      \
    _Pragma("unroll")                                                                 \
    for (int j = 0; j < 2; ++j) {                                                     \
        int c = j * 1024 + tid;                                                       \
        GLDS16((GSRC) + (size_t)(c >> 3) * 64 + (c & 7) * 8,                          \
               ldsb + (LOFF) + c * 16);                                               \
    }                                                                                 \
} while (0)

#define RDI_A(P) do { const uint8_t* _r = ldsb + ((P) * 2 + 0) * 16384;               \
    _Pragma("unroll")                                                                 \
    for (int m = 0; m < 4; ++m)                                                       \
        af[m] = *(const i32x4*)&_r[(wr * 64 + m * 16 + lr) * 64 + ls * 16];           \
} while (0)

#define RDI_B(P) do { const uint8_t* _r = ldsb + ((P) * 2 + 1) * 16384;               \
    _Pragma("unroll")                                                                 \
    for (int n = 0; n < 4; ++n)                                                       \
        bfr[n] = *(const i32x4*)&_r[(wc * 64 + n * 16 + lr) * 64 + ls * 16];          \
} while (0)

#define LDSV(DST, KT) do { _Pragma("unroll")                                          \
    for (int n = 0; n < 4; ++n)                                                       \
        DST[n] = sTc[(size_t)(KT) * 4096 + n * 16];                                   \
} while (0)

#define MFQI() do {                                                                   \
    __builtin_amdgcn_s_setprio(1);                                                    \
    _Pragma("unroll")                                                                 \
    for (int m = 0; m < 4; ++m)                                                       \
    _Pragma("unroll")                                                                 \
    for (int n = 0; n < 4; ++n) {                                                     \
        i32x4 zz = {0, 0, 0, 0};                                                      \
        i32x4 ic = __builtin_amdgcn_mfma_i32_16x16x64_i8(af[m], bfr[n], zz, 0, 0, 0); \
        _Pragma("unroll")                                                             \
        for (int r = 0; r < 4; ++r)                                                   \
            acc[m][n][r] += svc[n] * (float)ic[r];                                    \
    }                                                                                 \
    __builtin_amdgcn_s_setprio(0);                                                    \
} while (0)

#define CORR_PHASE(AOFF) do {                                                         \
    const uint16_t* _ax = (const uint16_t*)(ldsb + (AOFF));                           \
    const uint16_t* _bz = (const uint16_t*)(ldsb + 98304);                            \
    bf16x8 ah[2][4], bzv[2][4];                                                       \
    _Pragma("unroll")                                                                 \
    for (int ks = 0; ks < 2; ++ks) {                                                  \
        _Pragma("unroll")                                                             \
        for (int m = 0; m < 4; ++m)                                                   \
            ah[ks][m] = *(const bf16x8*)&_ax[(wr*64 + m*16 + lr)*64 + ks*32 + ls*8];  \
        _Pragma("unroll")                                                             \
        for (int n = 0; n < 4; ++n)                                                   \
            bzv[ks][n] = *(const bf16x8*)&_bz[(wc*64 + n*16 + lr)*64 + ks*32 + ls*8]; \
    }                                                                                 \
    LGKM0();                                                                          \
    __builtin_amdgcn_s_setprio(1);                                                    \
    _Pragma("unroll")                                                                 \
    for (int ks = 0; ks < 2; ++ks)                                                    \
    _Pragma("unroll")                                                                 \
    for (int m = 0; m < 4; ++m)                                                       \
    _Pragma("unroll")                                                                 \
    for (int n = 0; n < 4; ++n)                                                       \
        acc[m][n] = __builtin_amdgcn_mfma_f32_16x16x32_bf16(                          \
            ah[ks][m], bzv[ks][n], acc[m][n], 0, 0, 0);                               \
    __builtin_amdgcn_s_setprio(0);                                                    \
} while (0)

__global__ __launch_bounds__(1024, 4)
void gemm_kernel(const int8_t* __restrict__ xi,
                 const int8_t* __restrict__ Wi,
                 const float* __restrict__ sT,
                 const float* __restrict__ sx,
                 const uint16_t* __restrict__ xsh,
                 const uint16_t* __restrict__ xsl,
                 const uint16_t* __restrict__ zsneg,
                 float* __restrict__ C) {
    __shared__ uint8_t ldsb[131072];  // [0,64K) main i8 dbuf; [64K,96K) xs-hi;
                                      // [96K,128K) zsneg; xs-lo reuses [0,32K)

    const int tid  = threadIdx.x;
    const int wave = tid >> 6;
    const int lane = tid & 63;
    const int wr = wave >> 2;                  // 0..3 (M)
    const int wc = wave & 3;                   // 0..3 (N)
    const int lr = lane & 15;
    const int ls = lane >> 4;
    const int grow   = tid >> 2;               // 0..255 staging row
    const int slot16 = tid & 3;                // 16B slot in 64B row

    // XCD-aware swizzle: 256 wgs, 8 XCDs, 32 contiguous tiles per XCD
    int bid = blockIdx.x;
    int wg = (bid & 7) * 32 + (bid >> 3);
    const int bm0 = (wg >> 4) * 256;
    const int bn0 = (wg & 15) * 256;

    const int8_t* Ag = xi + (size_t)bm0 * KD;
    const int8_t* Bg = Wi + (size_t)bn0 * KD;
    const float*  sTc = sT + bn0 + wc * 64 + lr;
    const uint16_t* xshp = xsh + (size_t)bm0 * 64;
    const uint16_t* xslp = xsl + (size_t)bm0 * 64;
    const uint16_t* zsp  = zsneg + (size_t)bn0 * 64;

    f32x4 acc[4][4];
#pragma unroll
    for (int m = 0; m < 4; ++m)
#pragma unroll
        for (int n = 0; n < 4; ++n) {
            f32x4 z = {0.f, 0.f, 0.f, 0.f};
            acc[m][n] = z;
        }

    i32x4 af[4], bfr[4];
    float svc[4], svn[4];

    // prologue: stage tile 0 -> buf0; load tile-0 scales
    STI(Ag, 0, 0, 0);
    STI(Bg, 0, 1, 0);
    LDSV(svc, 0);
    VM(0);
    BAR();

#pragma unroll 1
    for (int t = 0; t < NT - 1; ++t) {          // tiles 0..62 (tail = 63)
        const int p = t & 1, q = p ^ 1;
        const int kn = (t + 1) * BK;
        STI(Ag, q, 0, kn);                      // stage tile t+1
        STI(Bg, q, 1, kn);
        LDSV(svn, t + 1);                       // next tile's column scales
        RDI_A(p); RDI_B(p);                     // 8 ds_read_b128
        LGKM0();
        MFQI();                                 // 16 i8-MFMA + scale-epilogue
        VM(0);
        BAR();
        svc[0] = svn[0]; svc[1] = svn[1]; svc[2] = svn[2]; svc[3] = svn[3];
    }
    // tail tile 63 (buf1) + stage correction operands (regions untouched)
    {
        ST_CORR(xshp, 65536);                   // xs-hi  -> [64K,96K)
        ST_CORR(zsp,  98304);                   // -s*z   -> [96K,128K)
        RDI_A(1); RDI_B(1);
        LGKM0();
        MFQI();
        VM(0);
        BAR();
    }
    // correction tile 1: acc += xs_hi x (-s*z); stage xs-lo into [0,32K)
    {
        ST_CORR(xslp, 0);
        CORR_PHASE(65536);
        VM(0);
        BAR();
    }
    // correction tile 2: acc += xs_lo x (-s*z)
    {
        CORR_PHASE(0);
    }

    // epilogue: y = sx[row] * acc.  D layout col=lane&15, row=(lane>>4)*4+r
    const int r0 = ls * 4;
#pragma unroll
    for (int m = 0; m < 4; ++m) {
        float4 sxv = *(const float4*)(sx + bm0 + wr * 64 + m * 16 + r0);
        float sxa[4] = {sxv.x, sxv.y, sxv.z, sxv.w};
#pragma unroll
        for (int n = 0; n < 4; ++n)
#pragma unroll
            for (int r = 0; r < 4; ++r) {
                int row = bm0 + wr * 64 + m * 16 + r0 + r;
                int col = bn0 + wc * 64 + n * 16 + lr;
                C[(size_t)row * ND + col] = acc[m][n][r] * sxa[r];
            }
    }
}

extern "C" void kernel_launch(void* const* d_in, const int* in_sizes, int n_in,
                              void* d_out, int out_size, void* d_ws, size_t ws_size,
                              hipStream_t stream) {
    const float* x     = (const float*)d_in[0];
    const int*   Wq    = (const int*)d_in[1];   // uint8 pushed as int32
    const float* scale = (const float*)d_in[2];
    const float* zero  = (const float*)d_in[3];
    float* out = (float*)d_out;

    char* ws = (char*)d_ws;
    int8_t*   xi    = (int8_t*)(ws);                                  // 16 MB
    int8_t*   Wi    = (int8_t*)(ws + (size_t)16 * 1024 * 1024);       // 16 MB
    float*    sT    = (float*)(ws + (size_t)32 * 1024 * 1024);        // 1 MB
    float*    sx    = (float*)(ws + (size_t)33 * 1024 * 1024);        // 16 KB
    uint16_t* xsh   = (uint16_t*)(ws + (size_t)34 * 1024 * 1024);     // 512 KB
    uint16_t* xsl   = (uint16_t*)(ws + (size_t)34 * 1024 * 1024 + 524288);
    uint16_t* zsneg = (uint16_t*)(ws + (size_t)35 * 1024 * 1024);     // 512 KB

    hipLaunchKernelGGL(xq_kernel, dim3(4096), dim3(256), 0, stream, x, xi, sx, xsh, xsl);
    hipLaunchKernelGGL(wq_kernel, dim3(4096), dim3(256), 0, stream, Wq, Wi);
    hipLaunchKernelGGL(sz_kernel, dim3(64), dim3(256), 0, stream, scale, zero, sT, zsneg);
    hipLaunchKernelGGL(gemm_kernel, dim3(256), dim3(1024), 0, stream,
                       xi, Wi, sT, sx, xsh, xsl, zsneg, out);
}

// Round 16
// 105.747 us; speedup vs baseline: 1.4439x; 1.4439x over previous
//
#include <hip/hip_runtime.h>
#include <stdint.h>

#define KD 4096
#define ND 4096
#define BK 64
#define NT 64            // K-tiles

typedef float f32x4 __attribute__((ext_vector_type(4)));
typedef int   i32x4 __attribute__((ext_vector_type(4)));

#define GLDS16(gp, lp) \
    __builtin_amdgcn_global_load_lds((const __attribute__((address_space(1))) void*)(gp), \
                                     (__attribute__((address_space(3))) void*)(lp), 16, 0, 0)

// ---------------------------------------------------------------------------
// xq: per-row quantize x (fp32) -> i8, sx = rowabsmax/127. (No group sums —
// zero-point is absorbed into the requantized weights.)
// ---------------------------------------------------------------------------
__global__ void xq_kernel(const float* __restrict__ x,
                          int8_t* __restrict__ xi,
                          float* __restrict__ sx) {
    const int r = blockIdx.x;
    const int t = threadIdx.x;           // 256 threads, 16 elems each
    const float4* xp = (const float4*)(x + (size_t)r * KD) + t * 4;
    float4 v0 = xp[0], v1 = xp[1], v2 = xp[2], v3 = xp[3];
    float vv[16] = {v0.x, v0.y, v0.z, v0.w, v1.x, v1.y, v1.z, v1.w,
                    v2.x, v2.y, v2.z, v2.w, v3.x, v3.y, v3.z, v3.w};
    float am = 0.f;
#pragma unroll
    for (int j = 0; j < 16; ++j) am = fmaxf(am, fabsf(vv[j]));
#pragma unroll
    for (int off = 32; off; off >>= 1) am = fmaxf(am, __shfl_xor(am, off));
    __shared__ float red[4];
    if ((t & 63) == 0) red[t >> 6] = am;
    __syncthreads();
    am = fmaxf(fmaxf(red[0], red[1]), fmaxf(red[2], red[3]));
    am = fmaxf(am, 1e-20f);
    const float inv = 127.f / am;
    uint32_t w[4];
#pragma unroll
    for (int p = 0; p < 4; ++p) {
        int q0 = __float2int_rn(vv[4*p]     * inv);
        int q1 = __float2int_rn(vv[4*p + 1] * inv);
        int q2 = __float2int_rn(vv[4*p + 2] * inv);
        int q3 = __float2int_rn(vv[4*p + 3] * inv);
        w[p] = (q0 & 255) | ((q1 & 255) << 8) | ((q2 & 255) << 16) |
               ((uint32_t)(q3 & 255) << 24);
    }
    uint4 pk = {w[0], w[1], w[2], w[3]};
    *(uint4*)(xi + (size_t)r * KD + t * 16) = pk;
    if (t == 0) sx[r] = am / 127.f;
}

// ---------------------------------------------------------------------------
// sc: per-output-column max |w| bound -> flat column scale sc[o].
// |w| <= s_g * max(z_g, 15 - z_g) per group; sc = max_g(...) / 127 ensures
// the requantized |u| <= 127 exactly (no clipping).
// ---------------------------------------------------------------------------
__global__ void sc_kernel(const float* __restrict__ scale,
                          const float* __restrict__ zero,
                          float* __restrict__ sc) {
    int o = blockIdx.x * 256 + threadIdx.x;    // 4096 outputs
    const float* sp = scale + (size_t)o * 64;
    const float* zp = zero + (size_t)o * 64;
    float mx = 0.f;
#pragma unroll 8
    for (int g = 0; g < 64; ++g) {
        float s = sp[g], z = zp[g];
        mx = fmaxf(mx, s * fmaxf(z, 15.f - z));
    }
    sc[o] = fmaxf(mx, 1e-20f) * (1.f / 127.f);
}

// ---------------------------------------------------------------------------
// wq: dequant (exact) then requantize to flat per-column i8:
// u = rint((q - z)*s / sc[o]) = rint(fma(q, a, b)), a = s/sc, b = -z*s/sc.
// Rows <2048 = high nibble of Wq[o*4096+k]; >=2048 = low nibble.
// ---------------------------------------------------------------------------
__global__ void wq_kernel(const int* __restrict__ Wq,
                          const float* __restrict__ scale,
                          const float* __restrict__ zero,
                          const float* __restrict__ sc,
                          int8_t* __restrict__ Wi) {
    int t = blockIdx.x * 256 + threadIdx.x;   // 1048576 threads x 8 ints
    int o  = t >> 9;
    int i0 = (t & 511) << 3;
    const uint4* wp = (const uint4*)Wq;
    uint4 pa = wp[t * 2], pb = wp[t * 2 + 1];
    uint32_t v[8] = {pa.x, pa.y, pa.z, pa.w, pb.x, pb.y, pb.z, pb.w};
    int gh = (o << 6) + (i0 >> 6);
    int gl = gh + (2048 << 6);
    float sh = scale[gh], zh = zero[gh];
    float sl = scale[gl], zl = zero[gl];
    float rch = 1.f / sc[o], rcl = 1.f / sc[o + 2048];
    float ah = sh * rch, bh = -zh * sh * rch;
    float al = sl * rcl, bl = -zl * sl * rcl;
    uint32_t hw[2] = {0, 0}, lw[2] = {0, 0};
#pragma unroll
    for (int j = 0; j < 8; ++j) {
        float qh = (float)((v[j] >> 4) & 15u);
        float ql = (float)(v[j] & 15u);
        int uh = __float2int_rn(fmaf(qh, ah, bh));
        int ul = __float2int_rn(fmaf(ql, al, bl));
        hw[j >> 2] |= (uint32_t)(uh & 255) << (8 * (j & 3));
        lw[j >> 2] |= (uint32_t)(ul & 255) << (8 * (j & 3));
    }
    uint2 h = {hw[0], hw[1]}, l = {lw[0], lw[1]};
    *(uint2*)(Wi + (size_t)o * KD + i0)          = h;
    *(uint2*)(Wi + (size_t)(o + 2048) * KD + i0) = l;
}

// ---------------------------------------------------------------------------
// Pure i8 GEMM: 256x256 tile, BK=64, 16 waves (4Mx4N of 64x64) @ 1024 thr.
// Integer accumulation in AGPRs across ALL of K (|acc| <= 4096*127*127 <
// 2^31); scales applied once in the final epilogue: y = sx[row]*sc[col]*acc.
// Per tile: 2 gload_lds + 8 ds_read_b128 + 16 mfma_i32_16x16x64_i8. R9-proven
// fences (one VM(0)+BAR per tile, opposite-buffer staging).
// LDS [2buf][2mat][256][64B] = 64 KiB with the PROVEN swizzle algebra at 16B
// granularity (R15 omitted it -> 9.96M conflicts): read slot ls^((lr>>1)&3),
// stage source pre-swizzle (tid&3)^((tid>>3)&3), linear dest (rule #21).
// ---------------------------------------------------------------------------
#define BAR()  asm volatile("s_barrier" ::: "memory")
#define LGKM0() do { asm volatile("s_waitcnt lgkmcnt(0)" ::: "memory"); \
                     __builtin_amdgcn_sched_barrier(0); } while (0)
#define VM(N)  asm volatile("s_waitcnt vmcnt(" #N ")" ::: "memory")

#define STI(GP, BUF, MAT, KB) \
    GLDS16((GP) + (size_t)grow * KD + (KB) + sslot * 16, \
           ldsb + ((BUF) * 2 + (MAT)) * 16384 + tid * 16)

#define RDI_A(P) do { const uint8_t* _r = ldsb + ((P) * 2 + 0) * 16384;               \
    _Pragma("unroll")                                                                 \
    for (int m = 0; m < 4; ++m)                                                       \
        af[m] = *(const i32x4*)&_r[(wr * 64 + m * 16 + lr) * 64 + sx16];              \
} while (0)

#define RDI_B(P) do { const uint8_t* _r = ldsb + ((P) * 2 + 1) * 16384;               \
    _Pragma("unroll")                                                                 \
    for (int n = 0; n < 4; ++n)                                                       \
        bfr[n] = *(const i32x4*)&_r[(wc * 64 + n * 16 + lr) * 64 + sx16];             \
} while (0)

#define MFQI() do {                                                                   \
    __builtin_amdgcn_s_setprio(1);                                                    \
    _Pragma("unroll")                                                                 \
    for (int m = 0; m < 4; ++m)                                                       \
    _Pragma("unroll")                                                                 \
    for (int n = 0; n < 4; ++n)                                                       \
        acc[m][n] = __builtin_amdgcn_mfma_i32_16x16x64_i8(                            \
            af[m], bfr[n], acc[m][n], 0, 0, 0);                                       \
    __builtin_amdgcn_s_setprio(0);                                                    \
} while (0)

__global__ __launch_bounds__(1024, 4)
void gemm_kernel(const int8_t* __restrict__ xi,
                 const int8_t* __restrict__ Wi,
                 const float* __restrict__ sx,
                 const float* __restrict__ sc,
                 float* __restrict__ C) {
    __shared__ uint8_t ldsb[65536];   // 64 KiB: [2 buf][2 mat][256][64]

    const int tid  = threadIdx.x;
    const int wave = tid >> 6;
    const int lane = tid & 63;
    const int wr = wave >> 2;                  // 0..3 (M)
    const int wc = wave & 3;                   // 0..3 (N)
    const int lr = lane & 15;
    const int ls = lane >> 4;
    const int sx16  = (ls ^ ((lr >> 1) & 3)) * 16;    // swizzled read byte-slot
    const int sslot = (tid & 3) ^ ((tid >> 3) & 3);   // stage source pre-swizzle
    const int grow  = tid >> 2;                       // 0..255 staging row

    // XCD-aware swizzle: 256 wgs, 8 XCDs, 32 contiguous tiles per XCD
    int bid = blockIdx.x;
    int wg = (bid & 7) * 32 + (bid >> 3);
    const int bm0 = (wg >> 4) * 256;
    const int bn0 = (wg & 15) * 256;

    const int8_t* Ag = xi + (size_t)bm0 * KD;
    const int8_t* Bg = Wi + (size_t)bn0 * KD;

    i32x4 acc[4][4];
#pragma unroll
    for (int m = 0; m < 4; ++m)
#pragma unroll
        for (int n = 0; n < 4; ++n) {
            i32x4 z = {0, 0, 0, 0};
            acc[m][n] = z;
        }

    i32x4 af[4], bfr[4];

    // prologue: stage tile 0 -> buf0
    STI(Ag, 0, 0, 0);
    STI(Bg, 0, 1, 0);
    VM(0);
    BAR();

#pragma unroll 1
    for (int t = 0; t < NT - 1; ++t) {          // tiles 0..62 (tail = 63)
        const int p = t & 1, q = p ^ 1;
        const int kn = (t + 1) * BK;
        STI(Ag, q, 0, kn);                      // stage tile t+1
        STI(Bg, q, 1, kn);
        RDI_A(p); RDI_B(p);                     // 8 ds_read_b128
        LGKM0();
        MFQI();                                 // 16 i8 MFMA, i32 acc
        VM(0);
        BAR();
    }
    // tail tile 63 (buf1)
    {
        RDI_A(1); RDI_B(1);
        LGKM0();
        MFQI();
    }

    // epilogue: y = sx[row] * sc[col] * acc.  D layout col=lane&15,
    // row=(lane>>4)*4+r  [m89/m91 — shape-determined, dtype-independent]
    const int r0 = ls * 4;
    float bscale[4];
#pragma unroll
    for (int n = 0; n < 4; ++n)
        bscale[n] = sc[bn0 + wc * 64 + n * 16 + lr];
#pragma unroll
    for (int m = 0; m < 4; ++m) {
        float4 sxv = *(const float4*)(sx + bm0 + wr * 64 + m * 16 + r0);
        float sxa[4] = {sxv.x, sxv.y, sxv.z, sxv.w};
#pragma unroll
        for (int n = 0; n < 4; ++n)
#pragma unroll
            for (int r = 0; r < 4; ++r) {
                int row = bm0 + wr * 64 + m * 16 + r0 + r;
                int col = bn0 + wc * 64 + n * 16 + lr;
                C[(size_t)row * ND + col] = (float)acc[m][n][r] * sxa[r] * bscale[n];
            }
    }
}

extern "C" void kernel_launch(void* const* d_in, const int* in_sizes, int n_in,
                              void* d_out, int out_size, void* d_ws, size_t ws_size,
                              hipStream_t stream) {
    const float* x     = (const float*)d_in[0];
    const int*   Wq    = (const int*)d_in[1];   // uint8 pushed as int32
    const float* scale = (const float*)d_in[2];
    const float* zero  = (const float*)d_in[3];
    float* out = (float*)d_out;

    char* ws = (char*)d_ws;
    int8_t* xi = (int8_t*)(ws);                                   // 16 MB
    int8_t* Wi = (int8_t*)(ws + (size_t)16 * 1024 * 1024);        // 16 MB
    float*  sx = (float*)(ws + (size_t)32 * 1024 * 1024);         // 16 KB
    float*  sc = (float*)(ws + (size_t)32 * 1024 * 1024 + 65536); // 16 KB

    hipLaunchKernelGGL(xq_kernel, dim3(4096), dim3(256), 0, stream, x, xi, sx);
    hipLaunchKernelGGL(sc_kernel, dim3(16), dim3(256), 0, stream, scale, zero, sc);
    hipLaunchKernelGGL(wq_kernel, dim3(4096), dim3(256), 0, stream, Wq, scale, zero, sc, Wi);
    hipLaunchKernelGGL(gemm_kernel, dim3(256), dim3(1024), 0, stream, xi, Wi, sx, sc, out);
}

// Round 17
// 98.774 us; speedup vs baseline: 1.5459x; 1.0706x over previous
//
#include <hip/hip_runtime.h>
#include <stdint.h>

#define KD 4096
#define ND 4096
#define BK 128
#define NT 32            // K-tiles (BK=128; flat-i8 GEMM is group-agnostic)

typedef float f32x4 __attribute__((ext_vector_type(4)));
typedef int   i32x4 __attribute__((ext_vector_type(4)));

#define GLDS16(gp, lp) \
    __builtin_amdgcn_global_load_lds((const __attribute__((address_space(1))) void*)(gp), \
                                     (__attribute__((address_space(3))) void*)(lp), 16, 0, 0)

// ---------------------------------------------------------------------------
// Merged prep launch 1: blocks [0,4096) = xq (per-row x -> i8, sx=absmax/127);
// blocks [4096,4112) = sc (per-column flat scale bound).
// ---------------------------------------------------------------------------
__global__ void xqsc_kernel(const float* __restrict__ x,
                            int8_t* __restrict__ xi,
                            float* __restrict__ sx,
                            const float* __restrict__ scale,
                            const float* __restrict__ zero,
                            float* __restrict__ sc) {
    if (blockIdx.x >= 4096) {
        int o = (blockIdx.x - 4096) * 256 + threadIdx.x;    // 4096 outputs
        const float* sp = scale + (size_t)o * 64;
        const float* zp = zero + (size_t)o * 64;
        float mx = 0.f;
#pragma unroll 8
        for (int g = 0; g < 64; ++g) {
            float s = sp[g], z = zp[g];
            mx = fmaxf(mx, s * fmaxf(z, 15.f - z));
        }
        sc[o] = fmaxf(mx, 1e-20f) * (1.f / 127.f);
        return;
    }
    const int r = blockIdx.x;
    const int t = threadIdx.x;           // 256 threads, 16 elems each
    const float4* xp = (const float4*)(x + (size_t)r * KD) + t * 4;
    float4 v0 = xp[0], v1 = xp[1], v2 = xp[2], v3 = xp[3];
    float vv[16] = {v0.x, v0.y, v0.z, v0.w, v1.x, v1.y, v1.z, v1.w,
                    v2.x, v2.y, v2.z, v2.w, v3.x, v3.y, v3.z, v3.w};
    float am = 0.f;
#pragma unroll
    for (int j = 0; j < 16; ++j) am = fmaxf(am, fabsf(vv[j]));
#pragma unroll
    for (int off = 32; off; off >>= 1) am = fmaxf(am, __shfl_xor(am, off));
    __shared__ float red[4];
    if ((t & 63) == 0) red[t >> 6] = am;
    __syncthreads();
    am = fmaxf(fmaxf(red[0], red[1]), fmaxf(red[2], red[3]));
    am = fmaxf(am, 1e-20f);
    const float inv = 127.f / am;
    uint32_t w[4];
#pragma unroll
    for (int p = 0; p < 4; ++p) {
        int q0 = __float2int_rn(vv[4*p]     * inv);
        int q1 = __float2int_rn(vv[4*p + 1] * inv);
        int q2 = __float2int_rn(vv[4*p + 2] * inv);
        int q3 = __float2int_rn(vv[4*p + 3] * inv);
        w[p] = (q0 & 255) | ((q1 & 255) << 8) | ((q2 & 255) << 16) |
               ((uint32_t)(q3 & 255) << 24);
    }
    uint4 pk = {w[0], w[1], w[2], w[3]};
    *(uint4*)(xi + (size_t)r * KD + t * 16) = pk;
    if (t == 0) sx[r] = am / 127.f;
}

// ---------------------------------------------------------------------------
// wq: dequant (exact) then requantize to flat per-column i8:
// u = rint(fma(q, s/sc, -z*s/sc)).  Rows <2048 = high nibble; >=2048 = low.
// ---------------------------------------------------------------------------
__global__ void wq_kernel(const int* __restrict__ Wq,
                          const float* __restrict__ scale,
                          const float* __restrict__ zero,
                          const float* __restrict__ sc,
                          int8_t* __restrict__ Wi) {
    int t = blockIdx.x * 256 + threadIdx.x;   // 1048576 threads x 8 ints
    int o  = t >> 9;
    int i0 = (t & 511) << 3;
    const uint4* wp = (const uint4*)Wq;
    uint4 pa = wp[t * 2], pb = wp[t * 2 + 1];
    uint32_t v[8] = {pa.x, pa.y, pa.z, pa.w, pb.x, pb.y, pb.z, pb.w};
    int gh = (o << 6) + (i0 >> 6);
    int gl = gh + (2048 << 6);
    float sh = scale[gh], zh = zero[gh];
    float sl = scale[gl], zl = zero[gl];
    float rch = 1.f / sc[o], rcl = 1.f / sc[o + 2048];
    float ah = sh * rch, bh = -zh * sh * rch;
    float al = sl * rcl, bl = -zl * sl * rcl;
    uint32_t hw[2] = {0, 0}, lw[2] = {0, 0};
#pragma unroll
    for (int j = 0; j < 8; ++j) {
        float qh = (float)((v[j] >> 4) & 15u);
        float ql = (float)(v[j] & 15u);
        int uh = __float2int_rn(fmaf(qh, ah, bh));
        int ul = __float2int_rn(fmaf(ql, al, bl));
        hw[j >> 2] |= (uint32_t)(uh & 255) << (8 * (j & 3));
        lw[j >> 2] |= (uint32_t)(ul & 255) << (8 * (j & 3));
    }
    uint2 h = {hw[0], hw[1]}, l = {lw[0], lw[1]};
    *(uint2*)(Wi + (size_t)o * KD + i0)          = h;
    *(uint2*)(Wi + (size_t)(o + 2048) * KD + i0) = l;
}

// ---------------------------------------------------------------------------
// Pure i8 GEMM, BK=128 (R16 had 64): 256x256 tile, 16 waves (4Mx4N of 64x64)
// @ 1024 thr.  Halves barriers/VM-drains/lockstep windows per K-byte — the
// measured ~900 cyc/tile sync exposure was the R16 residual.
// Per tile: 4 gload_lds/thread (A 2 + B 2), two 64-K windows of
// {8 ds_read_b128 -> lgkm0 -> 16 mfma_i32_16x16x64_i8}, one VM(0)+BAR.
// LDS [2buf][2mat][256][128B] = 128 KiB. Swizzle extends the proven algebra
// to 8 slots: LDS[r][s] = G[r][s^((r>>1)&7)]; read slot (kw*4+ls)^((lr>>1)&7)
// (wr*64+m*16 contribute 0 mod 8); stage source (tid&7)^((tid>>4)&7), linear
// dest (rule #21; rows r and r+128 share the same XOR since 64&7==0... (128>>1)&7=0).
// Integer acc across all K; y = sx[row]*sc[col]*acc in the final epilogue.
// ---------------------------------------------------------------------------
#define BAR()  asm volatile("s_barrier" ::: "memory")
#define LGKM0() do { asm volatile("s_waitcnt lgkmcnt(0)" ::: "memory"); \
                     __builtin_amdgcn_sched_barrier(0); } while (0)
#define VM(N)  asm volatile("s_waitcnt vmcnt(" #N ")" ::: "memory")

#define STI(GP, BUF, MAT, KB) do {                                                    \
    GLDS16((GP) + (size_t)grow * KD + (KB) + sslot * 16,                              \
           ldsb + ((BUF) * 2 + (MAT)) * 32768 + tid * 16);                            \
    GLDS16((GP) + (size_t)(grow + 128) * KD + (KB) + sslot * 16,                      \
           ldsb + ((BUF) * 2 + (MAT)) * 32768 + 16384 + tid * 16);                    \
} while (0)

#define RDI_A(P, KW) do { const uint8_t* _r = ldsb + ((P) * 2 + 0) * 32768;           \
    _Pragma("unroll")                                                                 \
    for (int m = 0; m < 4; ++m)                                                       \
        af[m] = *(const i32x4*)&_r[(wr * 64 + m * 16 + lr) * 128 + sxw[KW]];          \
} while (0)

#define RDI_B(P, KW) do { const uint8_t* _r = ldsb + ((P) * 2 + 1) * 32768;           \
    _Pragma("unroll")                                                                 \
    for (int n = 0; n < 4; ++n)                                                       \
        bfr[n] = *(const i32x4*)&_r[(wc * 64 + n * 16 + lr) * 128 + sxw[KW]];         \
} while (0)

#define MFQI() do {                                                                   \
    __builtin_amdgcn_s_setprio(1);                                                    \
    _Pragma("unroll")                                                                 \
    for (int m = 0; m < 4; ++m)                                                       \
    _Pragma("unroll")                                                                 \
    for (int n = 0; n < 4; ++n)                                                       \
        acc[m][n] = __builtin_amdgcn_mfma_i32_16x16x64_i8(                            \
            af[m], bfr[n], acc[m][n], 0, 0, 0);                                       \
    __builtin_amdgcn_s_setprio(0);                                                    \
} while (0)

__global__ __launch_bounds__(1024, 4)
void gemm_kernel(const int8_t* __restrict__ xi,
                 const int8_t* __restrict__ Wi,
                 const float* __restrict__ sx,
                 const float* __restrict__ sc,
                 float* __restrict__ C) {
    __shared__ uint8_t ldsb[131072];  // 128 KiB: [2 buf][2 mat][256][128]

    const int tid  = threadIdx.x;
    const int wave = tid >> 6;
    const int lane = tid & 63;
    const int wr = wave >> 2;                  // 0..3 (M)
    const int wc = wave & 3;                   // 0..3 (N)
    const int lr = lane & 15;
    const int ls = lane >> 4;
    const int xk = (lr >> 1) & 7;
    int sxw[2];
    sxw[0] = ((0 * 4 + ls) ^ xk) * 16;         // window-0 swizzled byte slot
    sxw[1] = ((1 * 4 + ls) ^ xk) * 16;         // window-1
    const int sslot = (tid & 7) ^ ((tid >> 4) & 7);   // stage source pre-swizzle
    const int grow  = tid >> 3;                       // 0..127 staging row

    // XCD-aware swizzle: 256 wgs, 8 XCDs, 32 contiguous tiles per XCD
    int bid = blockIdx.x;
    int wg = (bid & 7) * 32 + (bid >> 3);
    const int bm0 = (wg >> 4) * 256;
    const int bn0 = (wg & 15) * 256;

    const int8_t* Ag = xi + (size_t)bm0 * KD;
    const int8_t* Bg = Wi + (size_t)bn0 * KD;

    i32x4 acc[4][4];
#pragma unroll
    for (int m = 0; m < 4; ++m)
#pragma unroll
        for (int n = 0; n < 4; ++n) {
            i32x4 z = {0, 0, 0, 0};
            acc[m][n] = z;
        }

    i32x4 af[4], bfr[4];

    // prologue: stage tile 0 -> buf0
    STI(Ag, 0, 0, 0);
    STI(Bg, 0, 1, 0);
    VM(0);
    BAR();

#pragma unroll 1
    for (int t = 0; t < NT - 1; ++t) {          // tiles 0..30 (tail = 31)
        const int p = t & 1, q = p ^ 1;
        const int kn = (t + 1) * BK;
        STI(Ag, q, 0, kn);                      // stage tile t+1 (4 gload_lds)
        STI(Bg, q, 1, kn);
        RDI_A(p, 0); RDI_B(p, 0);               // window 0: 8 ds_read_b128
        LGKM0();
        MFQI();                                 // 16 i8 MFMA
        RDI_A(p, 1); RDI_B(p, 1);               // window 1
        LGKM0();
        MFQI();
        VM(0);                                  // stages ~1 tile deep -> free
        BAR();
    }
    // tail tile 31 (buf1)
    {
        RDI_A(1, 0); RDI_B(1, 0);
        LGKM0();
        MFQI();
        RDI_A(1, 1); RDI_B(1, 1);
        LGKM0();
        MFQI();
    }

    // epilogue: y = sx[row] * sc[col] * acc.  D layout col=lane&15,
    // row=(lane>>4)*4+r  [m89/m91 — shape-determined, dtype-independent]
    const int r0 = ls * 4;
    float bscale[4];
#pragma unroll
    for (int n = 0; n < 4; ++n)
        bscale[n] = sc[bn0 + wc * 64 + n * 16 + lr];
#pragma unroll
    for (int m = 0; m < 4; ++m) {
        float4 sxv = *(const float4*)(sx + bm0 + wr * 64 + m * 16 + r0);
        float sxa[4] = {sxv.x, sxv.y, sxv.z, sxv.w};
#pragma unroll
        for (int n = 0; n < 4; ++n)
#pragma unroll
            for (int r = 0; r < 4; ++r) {
                int row = bm0 + wr * 64 + m * 16 + r0 + r;
                int col = bn0 + wc * 64 + n * 16 + lr;
                C[(size_t)row * ND + col] = (float)acc[m][n][r] * sxa[r] * bscale[n];
            }
    }
}

extern "C" void kernel_launch(void* const* d_in, const int* in_sizes, int n_in,
                              void* d_out, int out_size, void* d_ws, size_t ws_size,
                              hipStream_t stream) {
    const float* x     = (const float*)d_in[0];
    const int*   Wq    = (const int*)d_in[1];   // uint8 pushed as int32
    const float* scale = (const float*)d_in[2];
    const float* zero  = (const float*)d_in[3];
    float* out = (float*)d_out;

    char* ws = (char*)d_ws;
    int8_t* xi = (int8_t*)(ws);                                   // 16 MB
    int8_t* Wi = (int8_t*)(ws + (size_t)16 * 1024 * 1024);        // 16 MB
    float*  sx = (float*)(ws + (size_t)32 * 1024 * 1024);         // 16 KB
    float*  sc = (float*)(ws + (size_t)32 * 1024 * 1024 + 65536); // 16 KB

    hipLaunchKernelGGL(xqsc_kernel, dim3(4112), dim3(256), 0, stream,
                       x, xi, sx, scale, zero, sc);
    hipLaunchKernelGGL(wq_kernel, dim3(4096), dim3(256), 0, stream, Wq, scale, zero, sc, Wi);
    hipLaunchKernelGGL(gemm_kernel, dim3(256), dim3(1024), 0, stream, xi, Wi, sx, sc, out);
}